// Round 12
// baseline (338.341 us; speedup 1.0000x reference)
//
#include <hip/hip_runtime.h>
#include <math.h>

#define NB_CLASSES 1024
#define SZ_EMBED 128
#define N_SAMPLES 262144
#define MTILE 64
#define CTILE 64
#define NBLOCKS (N_SAMPLES / MTILE)  // 4096
#define XSTRIDE 136  // bf16 elems; 272B row stride -> 2-way bank alias only (free per m136)

typedef __bf16 v8bf __attribute__((ext_vector_type(8)));
typedef float v4f __attribute__((ext_vector_type(4)));
typedef float v2f __attribute__((ext_vector_type(2)));

// exp(+-32*cos + 3.2) = exp2(46.166...*(+-cos) + 4.6166...)
#define EXP_A 46.16624130844683f
#define EXP_B 4.616624130844683f

// R20: hoist the per-iter shuffle+store tail out of the class loop.
//  - R19 state: main 135us, MfmaUtil 22, VALUBusy 49, Occ 40. Remaining
//    per-iter chain: vmcnt -> ds_read -> MFMA -> exp2 tree -> 2 SERIAL
//    __shfl_xor (DS, ~120cyc each) -> 4B store. The shuffle+store tail is
//    ~250-300cyc dead latency x16 iters.
//  - Fix: e_acc[16] per-lane accumulators (16-row partials per class);
//    per-iter epilogue ends at e_acc[ct] += v. Cross-quad shuffles + store
//    run ONCE post-loop (16 independent, pipelineable sequences). +16 VGPR:
//    144->160 stays in the 3-waves/SIMD bracket; statically indexed, fully
//    unrolled, no outer loop (R9/R12/R14 lessons respected).
//  - vmcnt ledger without in-loop stores: [4 STAGE(ct), 4 STAGE(ct+1)]
//    outstanding at the wait -> vmcnt(4) mid-loop, vmcnt(0) last iter.
//    Iter 0 passes through (STAGE(0) drained by post-extract barrier).
//  - s_setprio(1) around MFMA (T5): waves now autonomous -> role diversity
//    regime where setprio pays (null only in lockstep schedules).
//  - (total - main) pinned at 143-144us across all 4-dispatch variants;
//    R17 merge made it worse -> fixed overhead, not addressed further.
#define SMEM_BYTES 36096

__device__ __forceinline__ unsigned short f2bf(float f) {
    union { float f; unsigned u; } v; v.f = f;
    unsigned u = v.u;
    unsigned rounding = 0x7FFFu + ((u >> 16) & 1u);
    return (unsigned short)((u + rounding) >> 16);
}
__device__ __forceinline__ float bfbits_lo(unsigned u) {
    union { unsigned u; float f; } v; v.u = u << 16; return v.f;
}
__device__ __forceinline__ float bfbits_hi(unsigned u) {
    union { unsigned u; float f; } v; v.u = u & 0xffff0000u; return v.f;
}

__global__ __launch_bounds__(256) void norm_proxies_kernel(
    const float* __restrict__ proxies, unsigned short* __restrict__ pn,
    float* __restrict__ pg) {
    // blocks 0-7 zero pos_g(1024) | negd_g(1024) - replaces memset dispatch
    if (blockIdx.x < 8) pg[blockIdx.x * 256 + threadIdx.x] = 0.f;
    int wv = threadIdx.x >> 6;
    int lane = threadIdx.x & 63;
    int row = blockIdx.x * 4 + wv;  // grid = 256 -> rows 0..1023
    const float* src = proxies + (size_t)row * SZ_EMBED + lane * 2;
    float2 x = *(const float2*)src;
    float ss = x.x * x.x + x.y * x.y;
    #pragma unroll
    for (int off = 32; off; off >>= 1) ss += __shfl_xor(ss, off);
    float inv = rsqrtf(ss + 1e-12f);
    unsigned pk = (unsigned)f2bf(x.x * inv) | ((unsigned)f2bf(x.y * inv) << 16);
    *(unsigned*)(pn + (size_t)row * SZ_EMBED + lane * 2) = pk;
}

__global__ __launch_bounds__(256) void main_kernel(
    const float* __restrict__ X, const int* __restrict__ T,
    const unsigned short* __restrict__ Pn,
    float* __restrict__ partial_neg, float* __restrict__ pos_g,
    float* __restrict__ negd_g) {
    __shared__ __align__(16) char smem[SMEM_BYTES];
    // layout: [0..17408) xtile (64 x 136 bf16), ALIASED by bufA after extraction
    //         [17408..18432) psum  [18432..19456) dsum  [19456..19712) tT
    //         [19712..36096) bufB (16384 B)
    unsigned short* xtile = (unsigned short*)smem;
    float (*psum)[4] = (float(*)[4])(smem + 17408);
    float (*dsum)[4] = (float(*)[4])(smem + 18432);
    int* tT = (int*)(smem + 19456);

    const int t = threadIdx.x;
    const int lane = t & 63;
    const int wv = t >> 6;
    const int quad = lane >> 4;
    const int l15 = lane & 15;
    const int sample_base = blockIdx.x * MTILE;
    const int row = t >> 2, part = t & 3;  // 4 threads per sample row, 32 cols each
    const char* PnB = (const char*)Pn;

    // Stage B tile `tc` into buffer `b` (b=1 -> bufA@0, b=0 -> bufB@19712).
    // Wave wv stages its own 16 rows: linear LDS dest (wave-uniform base +
    // lane*16) + inverse-swizzled global source + swizzled read (rule #21).
#define STAGE(tc, b) do {                                                      \
        char* lb_ = smem + ((b) ? 0 : 19712) + wv * 4096;                      \
        _Pragma("unroll")                                                      \
        for (int c_ = 0; c_ < 4; ++c_) {                                       \
            int rw_ = c_ * 4 + (lane >> 4);                                    \
            const char* g_ = PnB + ((size_t)((tc) * 64 + wv * 16 + rw_)) * 256 \
                             + (((lane & 15) * 16) ^ ((rw_ & 7) << 4));        \
            __builtin_amdgcn_global_load_lds(                                  \
                (__attribute__((address_space(1))) const void*)g_,             \
                (__attribute__((address_space(3))) void*)(lb_ + c_ * 1024),    \
                16, 0, 0);                                                     \
        }                                                                      \
    } while (0)

    // issue tile-0 staging immediately (bufB, no alias); phase A barriers drain it
    STAGE(0, 0);

    // ---- phase A: load + normalize X tile into bf16 LDS; diag dot -> global atomics ----
    {
        const float4* src = (const float4*)(X + (size_t)(sample_base + row) * SZ_EMBED + part * 32);
        float4 r[8];
        float ss = 0.f;
        #pragma unroll
        for (int j = 0; j < 8; ++j) {
            r[j] = src[j];
            ss += r[j].x * r[j].x + r[j].y * r[j].y + r[j].z * r[j].z + r[j].w * r[j].w;
        }
        psum[row][part] = ss;
        if (t < MTILE) tT[t] = T[sample_base + t];
        __syncthreads();
        float inv = rsqrtf(psum[row][0] + psum[row][1] + psum[row][2] + psum[row][3] + 1e-12f);
        unsigned short* dst = xtile + row * XSTRIDE + part * 32;
        #pragma unroll
        for (int j = 0; j < 8; ++j) {
            uint2 pk;
            pk.x = (unsigned)f2bf(r[j].x * inv) | ((unsigned)f2bf(r[j].y * inv) << 16);
            pk.y = (unsigned)f2bf(r[j].z * inv) | ((unsigned)f2bf(r[j].w * inv) << 16);
            *(uint2*)(dst + j * 4) = pk;
        }
        // diag partial: dot(X[row]*inv, Pn[T[row]]) over this thread's 32 cols
        int lbl = tT[row];
        const unsigned short* prow = Pn + (size_t)lbl * SZ_EMBED + part * 32;
        float d = 0.f;
        #pragma unroll
        for (int j = 0; j < 4; ++j) {  // 4 x uint4 = 32 cols
            uint4 pv = *(const uint4*)(prow + j * 8);
            float4 xa = r[2 * j], xb = r[2 * j + 1];
            d += bfbits_lo(pv.x) * xa.x + bfbits_hi(pv.x) * xa.y;
            d += bfbits_lo(pv.y) * xa.z + bfbits_hi(pv.y) * xa.w;
            d += bfbits_lo(pv.z) * xb.x + bfbits_hi(pv.z) * xb.y;
            d += bfbits_lo(pv.w) * xb.z + bfbits_hi(pv.w) * xb.w;
        }
        dsum[row][part] = d * inv;
        __syncthreads();  // xtile + dsum ready (also drains tile-0 staging)
        if (part == 0) {
            int lbl2 = tT[row];
            float dd = dsum[row][0] + dsum[row][1] + dsum[row][2] + dsum[row][3];
            float dp = __builtin_amdgcn_exp2f(fmaf(dd, -EXP_A, EXP_B));  // exp(-a(cos-mrg))
            float dn = __builtin_amdgcn_exp2f(fmaf(dd,  EXP_A, EXP_B));  // exp(+a(cos+mrg))
            atomicAdd(&pos_g[lbl2], dp);   // only contribution to pos sums
            atomicAdd(&negd_g[lbl2], dn);  // subtracted from neg sums in finalize
        }
    }

    // ---- extract A fragments into registers (resident for whole class loop) ----
    v8bf afrag[4][4];
    #pragma unroll
    for (int ri = 0; ri < 4; ++ri)
        #pragma unroll
        for (int kc = 0; kc < 4; ++kc)
            afrag[ri][kc] = *(const v8bf*)(xtile + (ri * 16 + l15) * XSTRIDE + kc * 32 + quad * 8);

    // all waves done reading xtile -> bufA (alias) may now be written.
    // Compiler emits full vmcnt drain before this barrier -> vmcnt=0 at
    // class-loop entry for every wave (STAGE(0) complete).
    __syncthreads();

    // ---- class loop: barrier-free, store-free, wave-autonomous. Per-iter
    // VMEM ledger at the wait (oldest->newest): [4 loads STAGE(ct), 4 loads
    // STAGE(ct+1)] -> vmcnt(4) drains exactly STAGE(ct). Last iter: vmcnt(0).
    // Epilogue ends at e_acc[ct] += v; shuffles+stores hoisted post-loop.
    const int bswz = ((l15 & 7) << 4);
    const int browoff = (wv * 16 + l15) * 256;
    float e_acc[16];

    #pragma unroll
    for (int ct = 0; ct < NB_CLASSES / CTILE; ++ct) {
        const int cur = ct & 1;
        if (ct < NB_CLASSES / CTILE - 1) {
            STAGE(ct + 1, cur ^ 1);
            asm volatile("s_waitcnt vmcnt(4)" ::: "memory");
        } else {
            asm volatile("s_waitcnt vmcnt(0)" ::: "memory");
        }
        __builtin_amdgcn_sched_barrier(0);

        const char* bbase = smem + (cur ? 0 : 19712) + browoff;
        v8bf bfrag[4];
        #pragma unroll
        for (int kc = 0; kc < 4; ++kc)
            bfrag[kc] = *(const v8bf*)(bbase + ((kc * 64 + quad * 16) ^ bswz));

        v4f zero = {0.f, 0.f, 0.f, 0.f};
        v4f acc[4] = {zero, zero, zero, zero};
        __builtin_amdgcn_s_setprio(1);
        #pragma unroll
        for (int kc = 0; kc < 4; ++kc)
            #pragma unroll
            for (int ri = 0; ri < 4; ++ri)
                acc[ri] = __builtin_amdgcn_mfma_f32_16x16x32_bf16(afrag[ri][kc], bfrag[kc], acc[ri], 0, 0, 0);
        __builtin_amdgcn_s_setprio(0);

        // epilogue: 16 exp2, packed pairwise tree (7 v_pk_add_f32 + 1 scalar),
        // accumulate into this lane's 16-row partial for class ct*64+wv*16+l15.
        v2f e2[8];
        #pragma unroll
        for (int ri = 0; ri < 4; ++ri) {
            float a0 = __builtin_amdgcn_exp2f(fmaf(acc[ri][0], EXP_A, EXP_B));
            float a1 = __builtin_amdgcn_exp2f(fmaf(acc[ri][1], EXP_A, EXP_B));
            float a2 = __builtin_amdgcn_exp2f(fmaf(acc[ri][2], EXP_A, EXP_B));
            float a3 = __builtin_amdgcn_exp2f(fmaf(acc[ri][3], EXP_A, EXP_B));
            e2[ri * 2]     = (v2f){a0, a1};
            e2[ri * 2 + 1] = (v2f){a2, a3};
        }
        #pragma unroll
        for (int s2 = 4; s2; s2 >>= 1)
            #pragma unroll
            for (int j = 0; j < s2; ++j)
                e2[j] += e2[j + s2];
        e_acc[ct] = e2[0].x + e2[0].y;  // full assignment: one write per ct, statically indexed
    }
#undef STAGE

    // ---- post-loop: cross-quad reduce + store, 16 independent sequences
    // (pipelined; no per-iter serialization). quad-0 lanes write class
    // ct*64 + wv*16 + l15 of this block's partial row.
    float* nrow = partial_neg + (size_t)blockIdx.x * NB_CLASSES + wv * 16 + l15;
    #pragma unroll
    for (int ct = 0; ct < NB_CLASSES / CTILE; ++ct) {
        float v = e_acc[ct];
        v += __shfl_xor(v, 16);
        v += __shfl_xor(v, 32);
        if (quad == 0) nrow[ct * CTILE] = v;
    }
}

// 256 blocks, neg only. Block (g,q): sums rows [g*64, g*64+64) of class
// columns [q*256, q*256+256) into row g*64. 256 threads = 1 KB contiguous/row.
__global__ __launch_bounds__(256) void row_reduce_kernel(float* __restrict__ partial_neg) {
    const int t = threadIdx.x;
    const int g = blockIdx.x >> 2, q = blockIdx.x & 3;
    float* base = partial_neg + (size_t)g * 64 * NB_CLASSES + q * 256 + t;
    float s = 0.f;
    #pragma unroll 8
    for (int r = 0; r < 64; ++r) s += base[(size_t)r * NB_CLASSES];
    base[0] = s;
}

__global__ __launch_bounds__(256) void finalize_kernel(
    const float* __restrict__ partial_neg, const float* __restrict__ pos_g,
    const float* __restrict__ negd_g, float* __restrict__ out) {
    int t = threadIdx.x;
    // surviving neg rows: {0, 64, 128, ..., 4032}
    float4 ns = {0.f, 0.f, 0.f, 0.f};
    #pragma unroll 8
    for (int r = 0; r < 64; ++r) {
        float4 vn = *(const float4*)(partial_neg + (size_t)r * 64 * NB_CLASSES + 4 * t);
        ns.x += vn.x; ns.y += vn.y; ns.z += vn.z; ns.w += vn.w;
    }
    float4 nd = *(const float4*)(negd_g + 4 * t);
    ns.x -= nd.x; ns.y -= nd.y; ns.z -= nd.z; ns.w -= nd.w;
    float4 ps = *(const float4*)(pos_g + 4 * t);
    float lp_pos = log1pf(ps.x) + log1pf(ps.y) + log1pf(ps.z) + log1pf(ps.w);
    float lp_neg = log1pf(ns.x) + log1pf(ns.y) + log1pf(ns.z) + log1pf(ns.w);
    float valid = (ps.x != 0.f) + (ps.y != 0.f) + (ps.z != 0.f) + (ps.w != 0.f);
    #pragma unroll
    for (int off = 32; off; off >>= 1) {
        lp_pos += __shfl_xor(lp_pos, off);
        lp_neg += __shfl_xor(lp_neg, off);
        valid  += __shfl_xor(valid, off);
    }
    __shared__ float s[3][4];
    int wv = t >> 6, lane = t & 63;
    if (lane == 0) { s[0][wv] = lp_pos; s[1][wv] = lp_neg; s[2][wv] = valid; }
    __syncthreads();
    if (t == 0) {
        float P = s[0][0] + s[0][1] + s[0][2] + s[0][3];
        float Ng = s[1][0] + s[1][1] + s[1][2] + s[1][3];
        float V = s[2][0] + s[2][1] + s[2][2] + s[2][3];
        float pos_term = (V > 0.f) ? (P / fmaxf(V, 1.f)) : 0.f;
        float neg_term = Ng / (float)NB_CLASSES;
        out[0] = pos_term + neg_term;
        out[1] = pos_term;
        out[2] = neg_term;
    }
}

extern "C" void kernel_launch(void* const* d_in, const int* in_sizes, int n_in,
                              void* d_out, int out_size, void* d_ws, size_t ws_size,
                              hipStream_t stream) {
    const float* X = (const float*)d_in[0];
    const float* proxies = (const float*)d_in[1];
    const int* T = (const int*)d_in[2];
    float* out = (float*)d_out;

    // ws layout: Pn (256 KB) | pos_g (4 KB) | negd_g (4 KB) | partial_neg (16 MB)
    char* ws = (char*)d_ws;
    unsigned short* Pn = (unsigned short*)ws;
    float* pos_g = (float*)(ws + (size_t)NB_CLASSES * SZ_EMBED * sizeof(unsigned short));
    float* negd_g = pos_g + NB_CLASSES;
    float* partial_neg = negd_g + NB_CLASSES;

    norm_proxies_kernel<<<NB_CLASSES / 4, 256, 0, stream>>>(proxies, Pn, pos_g);
    main_kernel<<<NBLOCKS, 256, 0, stream>>>(X, T, Pn, partial_neg, pos_g, negd_g);
    row_reduce_kernel<<<256, 256, 0, stream>>>(partial_neg);
    finalize_kernel<<<1, 256, 0, stream>>>(partial_neg, pos_g, negd_g, out);
}

// Round 13
// 288.894 us; speedup vs baseline: 1.1712x; 1.1712x over previous
//
#include <hip/hip_runtime.h>
#include <math.h>

#define NB_CLASSES 1024
#define SZ_EMBED 128
#define N_SAMPLES 262144
#define MTILE 64
#define CTILE 64
#define NBLOCKS (N_SAMPLES / MTILE)  // 4096
#define XSTRIDE 136  // bf16 elems; 272B row stride -> 2-way bank alias only (free per m136)

typedef __bf16 v8bf __attribute__((ext_vector_type(8)));
typedef float v4f __attribute__((ext_vector_type(4)));
typedef float v2f __attribute__((ext_vector_type(2)));

// exp(+-32*cos + 3.2) = exp2(46.166...*(+-cos) + 4.6166...)
#define EXP_A 46.16624130844683f
#define EXP_B 4.616624130844683f

// R21: replace the whole partial-rows reduction path with direct atomics.
//  - R20 post-mortem: e_acc[16] pushed arch VGPR 64->172 (compiler pulled
//    MFMA state out of AGPRs to keep e_acc live), Occ 40->11%, main ->197.
//    IRON LAW confirmed 3x: no extra long-lived per-lane state in the
//    class loop. Class loop reverted to R19 exactly (135us, best).
//  - The 144us non-main budget exists only to sum 4096 partial rows.
//    Replace: per-iter store -> device atomicAdd into neg_total[1024]
//    (4KB). Each block: exactly 1024 atomics (one per class, already
//    cross-quad reduced) = minimal. Deletes 16MB partial write + 16.8MB
//    row_reduce read + the row_reduce dispatch; finalize reads 12KB.
//  - vmcnt ledger UNCHANGED: atomic-no-return = 1 wave VMEM op in the old
//    store's slot -> vmcnt(5) mid-loop / vmcnt(1) last iter.
//  - Pre-committed risk read: diag atomics showed ~32B HBM write-through
//    per atomic. If class atomics do too, WRITE balloons to ~150MB and
//    main slows ~10-15% -> revert to partials. If WRITE ~16-25MB, we
//    pocket ~40-60us of reduce-path cost.
#define SMEM_BYTES 36096

__device__ __forceinline__ unsigned short f2bf(float f) {
    union { float f; unsigned u; } v; v.f = f;
    unsigned u = v.u;
    unsigned rounding = 0x7FFFu + ((u >> 16) & 1u);
    return (unsigned short)((u + rounding) >> 16);
}
__device__ __forceinline__ float bfbits_lo(unsigned u) {
    union { unsigned u; float f; } v; v.u = u << 16; return v.f;
}
__device__ __forceinline__ float bfbits_hi(unsigned u) {
    union { unsigned u; float f; } v; v.u = u & 0xffff0000u; return v.f;
}

__global__ __launch_bounds__(256) void norm_proxies_kernel(
    const float* __restrict__ proxies, unsigned short* __restrict__ pn,
    float* __restrict__ pg) {
    // blocks 0-11 zero pos_g(1024) | negd_g(1024) | neg_total(1024)
    if (blockIdx.x < 12) pg[blockIdx.x * 256 + threadIdx.x] = 0.f;
    int wv = threadIdx.x >> 6;
    int lane = threadIdx.x & 63;
    int row = blockIdx.x * 4 + wv;  // grid = 256 -> rows 0..1023
    const float* src = proxies + (size_t)row * SZ_EMBED + lane * 2;
    float2 x = *(const float2*)src;
    float ss = x.x * x.x + x.y * x.y;
    #pragma unroll
    for (int off = 32; off; off >>= 1) ss += __shfl_xor(ss, off);
    float inv = rsqrtf(ss + 1e-12f);
    unsigned pk = (unsigned)f2bf(x.x * inv) | ((unsigned)f2bf(x.y * inv) << 16);
    *(unsigned*)(pn + (size_t)row * SZ_EMBED + lane * 2) = pk;
}

__global__ __launch_bounds__(256) void main_kernel(
    const float* __restrict__ X, const int* __restrict__ T,
    const unsigned short* __restrict__ Pn,
    float* __restrict__ neg_total, float* __restrict__ pos_g,
    float* __restrict__ negd_g) {
    __shared__ __align__(16) char smem[SMEM_BYTES];
    // layout: [0..17408) xtile (64 x 136 bf16), ALIASED by bufA after extraction
    //         [17408..18432) psum  [18432..19456) dsum  [19456..19712) tT
    //         [19712..36096) bufB (16384 B)
    unsigned short* xtile = (unsigned short*)smem;
    float (*psum)[4] = (float(*)[4])(smem + 17408);
    float (*dsum)[4] = (float(*)[4])(smem + 18432);
    int* tT = (int*)(smem + 19456);

    const int t = threadIdx.x;
    const int lane = t & 63;
    const int wv = t >> 6;
    const int quad = lane >> 4;
    const int l15 = lane & 15;
    const int sample_base = blockIdx.x * MTILE;
    const int row = t >> 2, part = t & 3;  // 4 threads per sample row, 32 cols each
    const char* PnB = (const char*)Pn;

    // Stage B tile `tc` into buffer `b` (b=1 -> bufA@0, b=0 -> bufB@19712).
    // Wave wv stages its own 16 rows: linear LDS dest (wave-uniform base +
    // lane*16) + inverse-swizzled global source + swizzled read (rule #21).
#define STAGE(tc, b) do {                                                      \
        char* lb_ = smem + ((b) ? 0 : 19712) + wv * 4096;                      \
        _Pragma("unroll")                                                      \
        for (int c_ = 0; c_ < 4; ++c_) {                                       \
            int rw_ = c_ * 4 + (lane >> 4);                                    \
            const char* g_ = PnB + ((size_t)((tc) * 64 + wv * 16 + rw_)) * 256 \
                             + (((lane & 15) * 16) ^ ((rw_ & 7) << 4));        \
            __builtin_amdgcn_global_load_lds(                                  \
                (__attribute__((address_space(1))) const void*)g_,             \
                (__attribute__((address_space(3))) void*)(lb_ + c_ * 1024),    \
                16, 0, 0);                                                     \
        }                                                                      \
    } while (0)

    // issue tile-0 staging immediately (bufB, no alias); phase A barriers drain it
    STAGE(0, 0);

    // ---- phase A: load + normalize X tile into bf16 LDS; diag dot -> global atomics ----
    {
        const float4* src = (const float4*)(X + (size_t)(sample_base + row) * SZ_EMBED + part * 32);
        float4 r[8];
        float ss = 0.f;
        #pragma unroll
        for (int j = 0; j < 8; ++j) {
            r[j] = src[j];
            ss += r[j].x * r[j].x + r[j].y * r[j].y + r[j].z * r[j].z + r[j].w * r[j].w;
        }
        psum[row][part] = ss;
        if (t < MTILE) tT[t] = T[sample_base + t];
        __syncthreads();
        float inv = rsqrtf(psum[row][0] + psum[row][1] + psum[row][2] + psum[row][3] + 1e-12f);
        unsigned short* dst = xtile + row * XSTRIDE + part * 32;
        #pragma unroll
        for (int j = 0; j < 8; ++j) {
            uint2 pk;
            pk.x = (unsigned)f2bf(r[j].x * inv) | ((unsigned)f2bf(r[j].y * inv) << 16);
            pk.y = (unsigned)f2bf(r[j].z * inv) | ((unsigned)f2bf(r[j].w * inv) << 16);
            *(uint2*)(dst + j * 4) = pk;
        }
        // diag partial: dot(X[row]*inv, Pn[T[row]]) over this thread's 32 cols
        int lbl = tT[row];
        const unsigned short* prow = Pn + (size_t)lbl * SZ_EMBED + part * 32;
        float d = 0.f;
        #pragma unroll
        for (int j = 0; j < 4; ++j) {  // 4 x uint4 = 32 cols
            uint4 pv = *(const uint4*)(prow + j * 8);
            float4 xa = r[2 * j], xb = r[2 * j + 1];
            d += bfbits_lo(pv.x) * xa.x + bfbits_hi(pv.x) * xa.y;
            d += bfbits_lo(pv.y) * xa.z + bfbits_hi(pv.y) * xa.w;
            d += bfbits_lo(pv.z) * xb.x + bfbits_hi(pv.z) * xb.y;
            d += bfbits_lo(pv.w) * xb.z + bfbits_hi(pv.w) * xb.w;
        }
        dsum[row][part] = d * inv;
        __syncthreads();  // xtile + dsum ready (also drains tile-0 staging)
        if (part == 0) {
            int lbl2 = tT[row];
            float dd = dsum[row][0] + dsum[row][1] + dsum[row][2] + dsum[row][3];
            float dp = __builtin_amdgcn_exp2f(fmaf(dd, -EXP_A, EXP_B));  // exp(-a(cos-mrg))
            float dn = __builtin_amdgcn_exp2f(fmaf(dd,  EXP_A, EXP_B));  // exp(+a(cos+mrg))
            atomicAdd(&pos_g[lbl2], dp);   // only contribution to pos sums
            atomicAdd(&negd_g[lbl2], dn);  // subtracted from neg sums in finalize
        }
    }

    // ---- extract A fragments into registers (resident for whole class loop) ----
    v8bf afrag[4][4];
    #pragma unroll
    for (int ri = 0; ri < 4; ++ri)
        #pragma unroll
        for (int kc = 0; kc < 4; ++kc)
            afrag[ri][kc] = *(const v8bf*)(xtile + (ri * 16 + l15) * XSTRIDE + kc * 32 + quad * 8);

    // all waves done reading xtile -> bufA (alias) may now be written.
    // Compiler emits full vmcnt drain before this barrier -> vmcnt=0 at
    // class-loop entry for every wave (STAGE(0) complete).
    __syncthreads();

    // ---- class loop: barrier-free, wave-autonomous (R19 schedule, verbatim
    // except store -> atomicAdd). Per-iter VMEM ledger at the wait (oldest->
    // newest): [4 loads STAGE(ct), atomic(ct-1), 4 loads STAGE(ct+1)].
    // vmcnt(5) drains exactly STAGE(ct); the atomic is never waited young.
    float* ng = neg_total + wv * 16 + l15;
    const int bswz = ((l15 & 7) << 4);
    const int browoff = (wv * 16 + l15) * 256;

    #pragma unroll
    for (int ct = 0; ct < NB_CLASSES / CTILE; ++ct) {
        const int cur = ct & 1;
        if (ct < NB_CLASSES / CTILE - 1) {
            STAGE(ct + 1, cur ^ 1);
            asm volatile("s_waitcnt vmcnt(5)" ::: "memory");
        } else {
            asm volatile("s_waitcnt vmcnt(1)" ::: "memory");  // drain STAGE(15), skip atomic(14)
        }
        __builtin_amdgcn_sched_barrier(0);

        const char* bbase = smem + (cur ? 0 : 19712) + browoff;
        v8bf bfrag[4];
        #pragma unroll
        for (int kc = 0; kc < 4; ++kc)
            bfrag[kc] = *(const v8bf*)(bbase + ((kc * 64 + quad * 16) ^ bswz));

        v4f zero = {0.f, 0.f, 0.f, 0.f};
        v4f acc[4] = {zero, zero, zero, zero};
        #pragma unroll
        for (int kc = 0; kc < 4; ++kc)
            #pragma unroll
            for (int ri = 0; ri < 4; ++ri)
                acc[ri] = __builtin_amdgcn_mfma_f32_16x16x32_bf16(afrag[ri][kc], bfrag[kc], acc[ri], 0, 0, 0);

        // epilogue: 16 exp2, packed pairwise tree (7 v_pk_add_f32 + 1 scalar),
        // cross-quad butterfly, one 4B atomicAdd per quad-0 lane.
        v2f e2[8];
        #pragma unroll
        for (int ri = 0; ri < 4; ++ri) {
            float a0 = __builtin_amdgcn_exp2f(fmaf(acc[ri][0], EXP_A, EXP_B));
            float a1 = __builtin_amdgcn_exp2f(fmaf(acc[ri][1], EXP_A, EXP_B));
            float a2 = __builtin_amdgcn_exp2f(fmaf(acc[ri][2], EXP_A, EXP_B));
            float a3 = __builtin_amdgcn_exp2f(fmaf(acc[ri][3], EXP_A, EXP_B));
            e2[ri * 2]     = (v2f){a0, a1};
            e2[ri * 2 + 1] = (v2f){a2, a3};
        }
        #pragma unroll
        for (int s2 = 4; s2; s2 >>= 1)
            #pragma unroll
            for (int j = 0; j < s2; ++j)
                e2[j] += e2[j + s2];
        float v = e2[0].x + e2[0].y;
        v += __shfl_xor(v, 16);
        v += __shfl_xor(v, 32);
        if (quad == 0) atomicAdd(ng + ct * CTILE, v);
    }
#undef STAGE
}

// Single small block: neg sums already in neg_total (atomics). 1024 classes,
// 4 per thread via float4. Total read: 12 KB.
__global__ __launch_bounds__(256) void finalize_kernel(
    const float* __restrict__ neg_total, const float* __restrict__ pos_g,
    const float* __restrict__ negd_g, float* __restrict__ out) {
    int t = threadIdx.x;
    float4 ns = *(const float4*)(neg_total + 4 * t);
    float4 nd = *(const float4*)(negd_g + 4 * t);
    ns.x -= nd.x; ns.y -= nd.y; ns.z -= nd.z; ns.w -= nd.w;
    float4 ps = *(const float4*)(pos_g + 4 * t);
    float lp_pos = log1pf(ps.x) + log1pf(ps.y) + log1pf(ps.z) + log1pf(ps.w);
    float lp_neg = log1pf(ns.x) + log1pf(ns.y) + log1pf(ns.z) + log1pf(ns.w);
    float valid = (ps.x != 0.f) + (ps.y != 0.f) + (ps.z != 0.f) + (ps.w != 0.f);
    #pragma unroll
    for (int off = 32; off; off >>= 1) {
        lp_pos += __shfl_xor(lp_pos, off);
        lp_neg += __shfl_xor(lp_neg, off);
        valid  += __shfl_xor(valid, off);
    }
    __shared__ float s[3][4];
    int wv = t >> 6, lane = t & 63;
    if (lane == 0) { s[0][wv] = lp_pos; s[1][wv] = lp_neg; s[2][wv] = valid; }
    __syncthreads();
    if (t == 0) {
        float P = s[0][0] + s[0][1] + s[0][2] + s[0][3];
        float Ng = s[1][0] + s[1][1] + s[1][2] + s[1][3];
        float V = s[2][0] + s[2][1] + s[2][2] + s[2][3];
        float pos_term = (V > 0.f) ? (P / fmaxf(V, 1.f)) : 0.f;
        float neg_term = Ng / (float)NB_CLASSES;
        out[0] = pos_term + neg_term;
        out[1] = pos_term;
        out[2] = neg_term;
    }
}

extern "C" void kernel_launch(void* const* d_in, const int* in_sizes, int n_in,
                              void* d_out, int out_size, void* d_ws, size_t ws_size,
                              hipStream_t stream) {
    const float* X = (const float*)d_in[0];
    const float* proxies = (const float*)d_in[1];
    const int* T = (const int*)d_in[2];
    float* out = (float*)d_out;

    // ws layout: Pn (256 KB) | pos_g (4 KB) | negd_g (4 KB) | neg_total (4 KB)
    char* ws = (char*)d_ws;
    unsigned short* Pn = (unsigned short*)ws;
    float* pos_g = (float*)(ws + (size_t)NB_CLASSES * SZ_EMBED * sizeof(unsigned short));
    float* negd_g = pos_g + NB_CLASSES;
    float* neg_total = negd_g + NB_CLASSES;

    norm_proxies_kernel<<<NB_CLASSES / 4, 256, 0, stream>>>(proxies, Pn, pos_g);
    main_kernel<<<NBLOCKS, 256, 0, stream>>>(X, T, Pn, neg_total, pos_g, negd_g);
    finalize_kernel<<<1, 256, 0, stream>>>(neg_total, pos_g, negd_g, out);
}